// Round 1
// baseline (210.414 us; speedup 1.0000x reference)
//
#include <hip/hip_runtime.h>
#include <cstdint>

typedef unsigned short u16;
typedef __bf16 bf16x8 __attribute__((ext_vector_type(8)));
typedef float f32x4 __attribute__((ext_vector_type(4)));

#define NB 8192          // batch rows
#define HD 512           // hidden
#define KD 1024          // IN + H
#define ND 2048          // 4H (physical, column-reordered)
#define HY_OFF (NB * HD) // offset of cy in d_out

// ---------- helpers ----------
__device__ __forceinline__ u16 f2bf(float f) {
  unsigned u = __float_as_uint(f);
  u += 0x7FFFu + ((u >> 16) & 1u);          // round-to-nearest-even bf16
  return (u16)(u >> 16);
}
__device__ __forceinline__ float bf2f(u16 h) {
  return __uint_as_float(((unsigned)h) << 16);
}
__device__ __forceinline__ void atomicMaxF(float* a, float v) {
  if (v >= 0.f) atomicMax((int*)a, __float_as_int(v));
  else          atomicMin((unsigned int*)a, __float_as_uint(v));
}
__device__ __forceinline__ float fq_u(float x) {           // unsigned 8-bit fake-quant
  float xc = fminf(fmaxf(x, 0.0f), 1.0f);
  return rintf(xc * 256.0f) * (1.0f / 256.0f);
}
__device__ __forceinline__ float fq_s(float x) {           // signed 8-bit fake-quant
  const float lim = 1.0f - 1.0f / 128.0f;
  float xc = fminf(fmaxf(x, -lim), lim);
  return rintf(xc * 128.0f) * (1.0f / 128.0f);
}
__device__ __forceinline__ float sigm(float x) { return 1.0f / (1.0f + expf(-x)); }

__device__ __forceinline__ void gload_lds16(const u16* g, u16* l) {
  __builtin_amdgcn_global_load_lds(
      (const __attribute__((address_space(1))) void*)g,
      (__attribute__((address_space(3))) void*)l, 16, 0, 0);
}

// ---------- max reductions (4 tensors -> maxes[0..3]) ----------
__global__ __launch_bounds__(256) void k_reduce_max(
    const float* __restrict__ w_ih, const float* __restrict__ w_hh,
    const float* __restrict__ b_ih, const float* __restrict__ b_hh,
    float* __restrict__ maxes) {
  int bid = blockIdx.x;
  const float* src; int slot, base;
  if (bid < 1024)      { src = w_ih; slot = 0; base = bid * 1024; }
  else if (bid < 2048) { src = w_hh; slot = 1; base = (bid - 1024) * 1024; }
  else if (bid < 2050) { src = b_ih; slot = 2; base = (bid - 2048) * 1024; }
  else                 { src = b_hh; slot = 3; base = (bid - 2050) * 1024; }
  float m = -INFINITY;
  for (int i = threadIdx.x; i < 1024; i += 256) m = fmaxf(m, src[base + i]);
  for (int k = 1; k < 64; k <<= 1) m = fmaxf(m, __shfl_xor(m, k, 64));
  __shared__ float sm[4];
  if ((threadIdx.x & 63) == 0) sm[threadIdx.x >> 6] = m;
  __syncthreads();
  if (threadIdx.x == 0) {
    m = fmaxf(fmaxf(sm[0], sm[1]), fmaxf(sm[2], sm[3]));
    atomicMaxF(&maxes[slot], m);
  }
}

// ---------- split X = [input | hx] into bf16 hi/lo, row-major [8192][1024] ----------
__global__ __launch_bounds__(256) void k_split_x(
    const float* __restrict__ input, const float* __restrict__ hx,
    u16* __restrict__ Xhi, u16* __restrict__ Xlo) {
  const int total4 = NB * KD / 4;
  for (int e4 = blockIdx.x * 256 + threadIdx.x; e4 < total4; e4 += gridDim.x * 256) {
    int row = e4 >> 8;       // /256
    int c4  = e4 & 255;
    float4 v = (c4 < 128)
        ? reinterpret_cast<const float4*>(input)[row * 128 + c4]
        : reinterpret_cast<const float4*>(hx)[row * 128 + (c4 - 128)];
    float xs[4] = {v.x, v.y, v.z, v.w};
    ushort4 hi, lo;
    u16 h0 = f2bf(xs[0]); u16 l0 = f2bf(xs[0] - bf2f(h0));
    u16 h1 = f2bf(xs[1]); u16 l1 = f2bf(xs[1] - bf2f(h1));
    u16 h2 = f2bf(xs[2]); u16 l2 = f2bf(xs[2] - bf2f(h2));
    u16 h3 = f2bf(xs[3]); u16 l3 = f2bf(xs[3] - bf2f(h3));
    hi.x = h0; hi.y = h1; hi.z = h2; hi.w = h3;
    lo.x = l0; lo.y = l1; lo.z = l2; lo.w = l3;
    reinterpret_cast<ushort4*>(Xhi)[e4] = hi;
    reinterpret_cast<ushort4*>(Xlo)[e4] = lo;
  }
}

// ---------- build W (noisy, transposed, column-reordered) hi/lo: [2048 j][1024 k] ----------
// physical col j = 64*hb + 16*g + hl  <->  logical col = g*512 + hb*16 + hl
__global__ __launch_bounds__(256) void k_build_w(
    const float* __restrict__ w_ih, const float* __restrict__ w_hh,
    const float* __restrict__ n_ih, const float* __restrict__ n_hh,
    const float* __restrict__ maxes,
    u16* __restrict__ Whi, u16* __restrict__ Wlo) {
  int j  = blockIdx.x;
  int g  = (j >> 4) & 3, hb = j >> 6, hl = j & 15;
  int col = g * 512 + (hb << 4) + hl;
  float s_ih = maxes[0] * 0.1f, s_hh = maxes[1] * 0.1f;
  int k = threadIdx.x * 4;
  float4 wv; float nv[4]; float s;
  if (k < 512) {
    wv = reinterpret_cast<const float4*>(w_ih)[(col * 512 + k) >> 2];
#pragma unroll
    for (int q = 0; q < 4; ++q) nv[q] = n_ih[(k + q) * ND + col];
    s = s_ih;
  } else {
    int kk = k - 512;
    wv = reinterpret_cast<const float4*>(w_hh)[(col * 512 + kk) >> 2];
#pragma unroll
    for (int q = 0; q < 4; ++q) nv[q] = n_hh[(kk + q) * ND + col];
    s = s_hh;
  }
  float xs[4] = {wv.x + nv[0] * s, wv.y + nv[1] * s, wv.z + nv[2] * s, wv.w + nv[3] * s};
  ushort4 hi, lo;
  u16 h0 = f2bf(xs[0]); u16 l0 = f2bf(xs[0] - bf2f(h0));
  u16 h1 = f2bf(xs[1]); u16 l1 = f2bf(xs[1] - bf2f(h1));
  u16 h2 = f2bf(xs[2]); u16 l2 = f2bf(xs[2] - bf2f(h2));
  u16 h3 = f2bf(xs[3]); u16 l3 = f2bf(xs[3] - bf2f(h3));
  hi.x = h0; hi.y = h1; hi.z = h2; hi.w = h3;
  lo.x = l0; lo.y = l1; lo.z = l2; lo.w = l3;
  reinterpret_cast<ushort4*>(Whi)[(j * KD + k) >> 2] = hi;
  reinterpret_cast<ushort4*>(Wlo)[(j * KD + k) >> 2] = lo;
}

// ---------- combined bias in physical column order ----------
__global__ __launch_bounds__(256) void k_build_bias(
    const float* __restrict__ b_ih, const float* __restrict__ b_hh,
    const float* __restrict__ nb_ih, const float* __restrict__ nb_hh,
    const float* __restrict__ maxes, float* __restrict__ biasC) {
  int j = blockIdx.x * 256 + threadIdx.x;
  if (j < ND) {
    int g = (j >> 4) & 3, hb = j >> 6, hl = j & 15;
    int col = g * 512 + (hb << 4) + hl;
    biasC[j] = b_ih[col] + nb_ih[col] * (maxes[2] * 0.1f)
             + b_hh[col] + nb_hh[col] * (maxes[3] * 0.1f);
  }
}

// ---------- GEMM (K=3072 split-bf16) + fused quantized-LSTM epilogue ----------
// grid 1024 = 64 (M/128) x 16 (N/128), 256 threads = 4 waves (2x2 of 64x64)
__global__ __launch_bounds__(256) void k_gemm_lstm(
    const u16* __restrict__ Xhi, const u16* __restrict__ Xlo,
    const u16* __restrict__ Whi, const u16* __restrict__ Wlo,
    const float* __restrict__ biasC, const float* __restrict__ cx,
    float* __restrict__ out) {
  __shared__ u16 Alds[128 * 32];
  __shared__ u16 Blds[128 * 32];
  const int tid = threadIdx.x;
  const int lane = tid & 63, wid = tid >> 6;
  const int wr = wid >> 1, wc = wid & 1;
  const int bm = blockIdx.x & 63, bn = blockIdx.x >> 6;
  const int mbase = bm * 128, nbase = bn * 128;
  const int lr = lane & 15, lg = lane >> 4;

  f32x4 acc[4][4] = {};

  for (int kt = 0; kt < 96; ++kt) {
    const int seg = kt >> 5;             // 0: hi*hi, 1: lo*hi, 2: hi*lo
    const int kcol = (kt & 31) * 32;
    const u16* Asrc = (seg == 1) ? Xlo : Xhi;
    const u16* Bsrc = (seg == 2) ? Wlo : Whi;
#pragma unroll
    for (int q = 0; q < 2; ++q) {
      const int idx = q * 256 + wid * 64 + lane;  // 16B chunk id
      const int row = idx >> 2, ch = idx & 3;
      gload_lds16(Asrc + (size_t)(mbase + row) * KD + kcol + ch * 8,
                  &Alds[(q * 256 + wid * 64) * 8]);
      gload_lds16(Bsrc + (size_t)(nbase + row) * KD + kcol + ch * 8,
                  &Blds[(q * 256 + wid * 64) * 8]);
    }
    __syncthreads();
    bf16x8 af[4], bfr[4];
#pragma unroll
    for (int m = 0; m < 4; ++m)
      af[m] = *reinterpret_cast<const bf16x8*>(&Alds[(wr * 64 + m * 16 + lr) * 32 + lg * 8]);
#pragma unroll
    for (int n = 0; n < 4; ++n)
      bfr[n] = *reinterpret_cast<const bf16x8*>(&Blds[(wc * 64 + n * 16 + lr) * 32 + lg * 8]);
#pragma unroll
    for (int m = 0; m < 4; ++m)
#pragma unroll
      for (int n = 0; n < 4; ++n)
        acc[m][n] = __builtin_amdgcn_mfma_f32_16x16x32_bf16(af[m], bfr[n], acc[m][n], 0, 0, 0);
    __syncthreads();
  }

  // epilogue: frag n == gate n; lane lr == h within this wave's 16-h group
  const int hb = bn * 2 + wc;
  const int h = hb * 16 + lr;
  const float bi = biasC[hb * 64 +  0 + lr];
  const float bf_ = biasC[hb * 64 + 16 + lr];
  const float bc = biasC[hb * 64 + 32 + lr];
  const float bo = biasC[hb * 64 + 48 + lr];
#pragma unroll
  for (int m = 0; m < 4; ++m) {
#pragma unroll
    for (int r = 0; r < 4; ++r) {
      const int row = mbase + wr * 64 + m * 16 + lg * 4 + r;
      const float gi = acc[m][0][r] + bi;
      const float gf = acc[m][1][r] + bf_;
      const float gc = acc[m][2][r] + bc;
      const float go = acc[m][3][r] + bo;
      const float ig = fq_u(sigm(gi));
      const float fg = fq_u(sigm(gf));
      const float cg = fq_s(tanhf(gc));
      const float og = fq_u(sigm(go));
      const float cxv = cx[(size_t)row * HD + h];
      const float t1 = fq_s(fg * cxv);
      const float t2 = fq_s(ig * cg);
      const float cyv = fq_s((t1 + t2) * 0.5f);
      const float hyv = fq_s(og * fq_s(tanhf(cyv * 2.0f)));
      out[(size_t)row * HD + h] = hyv;
      out[HY_OFF + (size_t)row * HD + h] = cyv;
    }
  }
}

// ---------- launch ----------
extern "C" void kernel_launch(void* const* d_in, const int* in_sizes, int n_in,
                              void* d_out, int out_size, void* d_ws, size_t ws_size,
                              hipStream_t stream) {
  const float* input = (const float*)d_in[0];
  const float* hx    = (const float*)d_in[1];
  const float* cx    = (const float*)d_in[2];
  const float* w_ih  = (const float*)d_in[3];
  const float* w_hh  = (const float*)d_in[4];
  const float* b_ih  = (const float*)d_in[5];
  const float* b_hh  = (const float*)d_in[6];
  const float* n_ih  = (const float*)d_in[7];
  const float* n_hh  = (const float*)d_in[8];
  const float* nb_ih = (const float*)d_in[9];
  const float* nb_hh = (const float*)d_in[10];
  float* out = (float*)d_out;

  char* ws = (char*)d_ws;
  float* maxes = (float*)ws;                                   // 16 B (+pad to 256)
  u16* Xhi = (u16*)(ws + 256);                                 // 16 MB
  u16* Xlo = (u16*)(ws + 256 + 16777216);                      // 16 MB
  u16* Whi = (u16*)(ws + 256 + 2 * 16777216);                  // 4 MB
  u16* Wlo = (u16*)(ws + 256 + 2 * 16777216 + 4194304);        // 4 MB
  float* biasC = (float*)(ws + 256 + 2 * 16777216 + 2 * 4194304); // 8 KB

  hipMemsetAsync(maxes, 0xFF, 16, stream);  // -NaN sentinel; atomic lattice fixes it
  hipLaunchKernelGGL(k_reduce_max, dim3(2052), dim3(256), 0, stream,
                     w_ih, w_hh, b_ih, b_hh, maxes);
  hipLaunchKernelGGL(k_split_x, dim3(2048), dim3(256), 0, stream, input, hx, Xhi, Xlo);
  hipLaunchKernelGGL(k_build_w, dim3(2048), dim3(256), 0, stream,
                     w_ih, w_hh, n_ih, n_hh, maxes, Whi, Wlo);
  hipLaunchKernelGGL(k_build_bias, dim3(8), dim3(256), 0, stream,
                     b_ih, b_hh, nb_ih, nb_hh, maxes, biasC);
  hipLaunchKernelGGL(k_gemm_lstm, dim3(1024), dim3(256), 0, stream,
                     Xhi, Xlo, Whi, Wlo, biasC, cx, out);
}

// Round 2
// 167.219 us; speedup vs baseline: 1.2583x; 1.2583x over previous
//
#include <hip/hip_runtime.h>
#include <cstdint>

typedef unsigned short u16;
typedef __bf16 bf16x8 __attribute__((ext_vector_type(8)));
typedef float f32x4 __attribute__((ext_vector_type(4)));

#define NB 8192          // batch rows
#define HD 512           // hidden
#define KD 1024          // IN + H
#define ND 2048          // 4H (physical, column-reordered)
#define HY_OFF (NB * HD) // offset of cy in d_out
#define NT 48            // K-tiles: 3 segments x 16 tiles of BK=64

// ---------- helpers ----------
__device__ __forceinline__ u16 f2bf(float f) {
  unsigned u = __float_as_uint(f);
  u += 0x7FFFu + ((u >> 16) & 1u);          // round-to-nearest-even bf16
  return (u16)(u >> 16);
}
__device__ __forceinline__ float bf2f(u16 h) {
  return __uint_as_float(((unsigned)h) << 16);
}
__device__ __forceinline__ void atomicMaxF(float* a, float v) {
  if (v >= 0.f) atomicMax((int*)a, __float_as_int(v));
  else          atomicMin((unsigned int*)a, __float_as_uint(v));
}
__device__ __forceinline__ float fq_u(float x) {           // unsigned 8-bit fake-quant
  float xc = fminf(fmaxf(x, 0.0f), 1.0f);
  return rintf(xc * 256.0f) * (1.0f / 256.0f);
}
__device__ __forceinline__ float fq_s(float x) {           // signed 8-bit fake-quant
  const float lim = 1.0f - 1.0f / 128.0f;
  float xc = fminf(fmaxf(x, -lim), lim);
  return rintf(xc * 128.0f) * (1.0f / 128.0f);
}
__device__ __forceinline__ float sigm(float x) { return 1.0f / (1.0f + expf(-x)); }

__device__ __forceinline__ void gload_lds16(const u16* g, u16* l) {
  __builtin_amdgcn_global_load_lds(
      (const __attribute__((address_space(1))) void*)g,
      (__attribute__((address_space(3))) void*)l, 16, 0, 0);
}

// ---------- max reductions (4 tensors -> maxes[0..3]) ----------
__global__ __launch_bounds__(256) void k_reduce_max(
    const float* __restrict__ w_ih, const float* __restrict__ w_hh,
    const float* __restrict__ b_ih, const float* __restrict__ b_hh,
    float* __restrict__ maxes) {
  int bid = blockIdx.x;
  const float* src; int slot, base;
  if (bid < 1024)      { src = w_ih; slot = 0; base = bid * 1024; }
  else if (bid < 2048) { src = w_hh; slot = 1; base = (bid - 1024) * 1024; }
  else if (bid < 2050) { src = b_ih; slot = 2; base = (bid - 2048) * 1024; }
  else                 { src = b_hh; slot = 3; base = (bid - 2050) * 1024; }
  float m = -INFINITY;
  for (int i = threadIdx.x; i < 1024; i += 256) m = fmaxf(m, src[base + i]);
  for (int k = 1; k < 64; k <<= 1) m = fmaxf(m, __shfl_xor(m, k, 64));
  __shared__ float sm[4];
  if ((threadIdx.x & 63) == 0) sm[threadIdx.x >> 6] = m;
  __syncthreads();
  if (threadIdx.x == 0) {
    m = fmaxf(fmaxf(sm[0], sm[1]), fmaxf(sm[2], sm[3]));
    atomicMaxF(&maxes[slot], m);
  }
}

// ---------- split X = [input | hx] into bf16 hi/lo, row-major [8192][1024] ----------
__global__ __launch_bounds__(256) void k_split_x(
    const float* __restrict__ input, const float* __restrict__ hx,
    u16* __restrict__ Xhi, u16* __restrict__ Xlo) {
  const int total4 = NB * KD / 4;
  for (int e4 = blockIdx.x * 256 + threadIdx.x; e4 < total4; e4 += gridDim.x * 256) {
    int row = e4 >> 8;       // /256
    int c4  = e4 & 255;
    float4 v = (c4 < 128)
        ? reinterpret_cast<const float4*>(input)[row * 128 + c4]
        : reinterpret_cast<const float4*>(hx)[row * 128 + (c4 - 128)];
    float xs[4] = {v.x, v.y, v.z, v.w};
    ushort4 hi, lo;
    u16 h0 = f2bf(xs[0]); u16 l0 = f2bf(xs[0] - bf2f(h0));
    u16 h1 = f2bf(xs[1]); u16 l1 = f2bf(xs[1] - bf2f(h1));
    u16 h2 = f2bf(xs[2]); u16 l2 = f2bf(xs[2] - bf2f(h2));
    u16 h3 = f2bf(xs[3]); u16 l3 = f2bf(xs[3] - bf2f(h3));
    hi.x = h0; hi.y = h1; hi.z = h2; hi.w = h3;
    lo.x = l0; lo.y = l1; lo.z = l2; lo.w = l3;
    reinterpret_cast<ushort4*>(Xhi)[e4] = hi;
    reinterpret_cast<ushort4*>(Xlo)[e4] = lo;
  }
}

// ---------- build W (noisy, transposed, column-reordered) hi/lo: [2048 j][1024 k] ----------
// physical j bits: [10:8]=bn, [7]=nh, [6:5]=wc, [4]=n2, [3:0]=lane
// gate g = 2*nh + n2 ; h-block hb = bn*4 + wc ; logical col = g*512 + hb*16 + lane
__global__ __launch_bounds__(256) void k_build_w(
    const float* __restrict__ w_ih, const float* __restrict__ w_hh,
    const float* __restrict__ n_ih, const float* __restrict__ n_hh,
    const float* __restrict__ maxes,
    u16* __restrict__ Whi, u16* __restrict__ Wlo) {
  int j  = blockIdx.x;
  int g  = ((j >> 7) & 1) * 2 + ((j >> 4) & 1);
  int hb = ((j >> 8) << 2) | ((j >> 5) & 3);
  int col = g * 512 + (hb << 4) + (j & 15);
  float s_ih = maxes[0] * 0.1f, s_hh = maxes[1] * 0.1f;
  int k = threadIdx.x * 4;
  float4 wv; float nv[4]; float s;
  if (k < 512) {
    wv = reinterpret_cast<const float4*>(w_ih)[(col * 512 + k) >> 2];
#pragma unroll
    for (int q = 0; q < 4; ++q) nv[q] = n_ih[(k + q) * ND + col];
    s = s_ih;
  } else {
    int kk = k - 512;
    wv = reinterpret_cast<const float4*>(w_hh)[(col * 512 + kk) >> 2];
#pragma unroll
    for (int q = 0; q < 4; ++q) nv[q] = n_hh[(kk + q) * ND + col];
    s = s_hh;
  }
  float xs[4] = {wv.x + nv[0] * s, wv.y + nv[1] * s, wv.z + nv[2] * s, wv.w + nv[3] * s};
  ushort4 hi, lo;
  u16 h0 = f2bf(xs[0]); u16 l0 = f2bf(xs[0] - bf2f(h0));
  u16 h1 = f2bf(xs[1]); u16 l1 = f2bf(xs[1] - bf2f(h1));
  u16 h2 = f2bf(xs[2]); u16 l2 = f2bf(xs[2] - bf2f(h2));
  u16 h3 = f2bf(xs[3]); u16 l3 = f2bf(xs[3] - bf2f(h3));
  hi.x = h0; hi.y = h1; hi.z = h2; hi.w = h3;
  lo.x = l0; lo.y = l1; lo.z = l2; lo.w = l3;
  reinterpret_cast<ushort4*>(Whi)[(j * KD + k) >> 2] = hi;
  reinterpret_cast<ushort4*>(Wlo)[(j * KD + k) >> 2] = lo;
}

// ---------- combined bias in physical column order ----------
__global__ __launch_bounds__(256) void k_build_bias(
    const float* __restrict__ b_ih, const float* __restrict__ b_hh,
    const float* __restrict__ nb_ih, const float* __restrict__ nb_hh,
    const float* __restrict__ maxes, float* __restrict__ biasC) {
  int j = blockIdx.x * 256 + threadIdx.x;
  if (j < ND) {
    int g  = ((j >> 7) & 1) * 2 + ((j >> 4) & 1);
    int hb = ((j >> 8) << 2) | ((j >> 5) & 3);
    int col = g * 512 + (hb << 4) + (j & 15);
    biasC[j] = b_ih[col] + nb_ih[col] * (maxes[2] * 0.1f)
             + b_hh[col] + nb_hh[col] * (maxes[3] * 0.1f);
  }
}

// ---------- GEMM 256x256-tile, BK=64, 8 waves, 4-phase/tile counted-vmcnt ----------
// grid 256 = 32 (M/256) x 8 (N/256); 512 threads; LDS 128 KiB (2 slots x (A+B))
// LDS swizzle: chunk' = chunk ^ (row&7), applied on gload SOURCE and ds_read addr.
__global__ __launch_bounds__(512, 2) void k_gemm_lstm(
    const u16* __restrict__ Xhi, const u16* __restrict__ Xlo,
    const u16* __restrict__ Whi, const u16* __restrict__ Wlo,
    const float* __restrict__ biasC, const float* __restrict__ cx,
    float* __restrict__ out) {
  __shared__ u16 L[2][2][16384];   // [slot][A=0/B=1][256 rows x 64 cols]
  const int tid  = threadIdx.x;
  const int lane = tid & 63, wid = tid >> 6;
  const int wr = wid >> 2, wc = wid & 3;       // 2 x 4 waves
  const int lr = lane & 15, lg = lane >> 4;
  const int bn = blockIdx.x & 7, bm = blockIdx.x >> 3;
  const int mbase = bm * 256, nbase = bn * 256;

  // staging constants (lane l -> row l>>3, lds chunk l&7, src chunk (l&7)^(l>>3))
  const int l8 = lane >> 3, l7 = lane & 7;
  const int choff = (l7 ^ l8) * 8;
  const int lrow0 = (wid * 2 + 0) * 8 + l8;
  const int lrow1 = (wid * 2 + 1) * 8 + l8;
  const int ldsw0 = (wid * 2 + 0) * 512;
  const int ldsw1 = (wid * 2 + 1) * 512;

  // frag-read swizzled chunk offsets (u16 units) for ks=0,1
  const int cA0 = ((0 * 4 + lg) ^ (lr & 7)) * 8;
  const int cA1 = ((1 * 4 + lg) ^ (lr & 7)) * 8;

  f32x4 acc[8][4] = {};     // [mh*4+m2][gate = 2*nh+n2]
  bf16x8 afr[4][2];         // [m2][ks], reused across the 2 nh-phases of one mh
  bf16x8 bfr[2][2][2];      // [nh][n2][ks]

#define STAGE(V, HALF, ISA)                                                     \
  {                                                                             \
    const int v_ = (V) > (NT - 1) ? (NT - 1) : (V);                             \
    const int seg_ = v_ >> 4, kc_ = (v_ & 15) * 64;                             \
    const u16* src_ = (ISA) ? (seg_ == 1 ? Xlo : Xhi)                           \
                            : (seg_ == 2 ? Wlo : Whi);                          \
    const int gb_ = ((ISA) ? mbase : nbase) + (HALF) * 128;                     \
    u16* dst_ = &L[(V) & 1][(ISA) ? 0 : 1][(HALF) * 8192];                      \
    gload_lds16(src_ + (size_t)(gb_ + lrow0) * KD + kc_ + choff, dst_ + ldsw0); \
    gload_lds16(src_ + (size_t)(gb_ + lrow1) * KD + kc_ + choff, dst_ + ldsw1); \
  }

#define PH(MH, NH, LOADA, LOADB, STAGE_CODE, WAIT_CODE)                         \
  {                                                                             \
    const u16* As_ = &L[s][0][0];                                               \
    const u16* Bs_ = &L[s][1][0];                                               \
    if (LOADA) {                                                                \
      _Pragma("unroll") for (int m2 = 0; m2 < 4; ++m2) {                        \
        const int ar = ((MH) * 128 + wr * 64 + m2 * 16 + lr) * 64;              \
        afr[m2][0] = *reinterpret_cast<const bf16x8*>(&As_[ar + cA0]);          \
        afr[m2][1] = *reinterpret_cast<const bf16x8*>(&As_[ar + cA1]);          \
      }                                                                         \
    }                                                                           \
    if (LOADB) {                                                                \
      _Pragma("unroll") for (int n2 = 0; n2 < 2; ++n2) {                        \
        const int br = ((NH) * 128 + wc * 32 + n2 * 16 + lr) * 64;              \
        bfr[(NH)][n2][0] = *reinterpret_cast<const bf16x8*>(&Bs_[br + cA0]);    \
        bfr[(NH)][n2][1] = *reinterpret_cast<const bf16x8*>(&Bs_[br + cA1]);    \
      }                                                                         \
    }                                                                           \
    STAGE_CODE;                                                                 \
    WAIT_CODE;                                                                  \
    __builtin_amdgcn_s_barrier();                                               \
    __builtin_amdgcn_s_setprio(1);                                              \
    _Pragma("unroll") for (int m2 = 0; m2 < 4; ++m2)                            \
      _Pragma("unroll") for (int n2 = 0; n2 < 2; ++n2) {                        \
        f32x4* ac = &acc[(MH) * 4 + m2][(NH) * 2 + n2];                         \
        *ac = __builtin_amdgcn_mfma_f32_16x16x32_bf16(afr[m2][0],               \
                  bfr[(NH)][n2][0], *ac, 0, 0, 0);                              \
        *ac = __builtin_amdgcn_mfma_f32_16x16x32_bf16(afr[m2][1],               \
                  bfr[(NH)][n2][1], *ac, 0, 0, 0);                              \
      }                                                                         \
    __builtin_amdgcn_s_setprio(0);                                              \
    __builtin_amdgcn_s_barrier();                                               \
  }

  // prologue: issue order A0(0), B1(0), B0(0), A1(0), A0(1), B1(1)
  STAGE(0, 0, 1);
  STAGE(0, 1, 0);
  STAGE(0, 0, 0);
  STAGE(0, 1, 1);
  STAGE(1, 0, 1);
  STAGE(1, 1, 0);
  asm volatile("s_waitcnt vmcnt(6)" ::: "memory");   // A0(0),B1(0),B0(0) landed
  __builtin_amdgcn_s_barrier();

  int s = 0;
  for (int u = 0; u < NT - 1; ++u, s ^= 1) {
    // ph0 (mh0,nh0): read A0-frags + B0-frags; stage B0(u+1)
    PH(0, 0, 1, 1, STAGE(u + 1, 0, 0), );
    // ph1 (mh0,nh1): read B1-frags; stage A1(u+1); vmcnt(8) covers A1(u)
    PH(0, 1, 0, 1, STAGE(u + 1, 1, 1),
       asm volatile("s_waitcnt vmcnt(8)" ::: "memory"));
    // ph2 (mh1,nh1): read A1-frags; stage A0(u+2)
    PH(1, 1, 1, 0, STAGE(u + 2, 0, 1), );
    // ph3 (mh1,nh0): re-read B0-frags; stage B1(u+2); vmcnt(6) covers B0(u+1)
    PH(1, 0, 0, 1, STAGE(u + 2, 1, 0),
       asm volatile("s_waitcnt vmcnt(6)" ::: "memory"));
  }
  // peeled tile 47 (s == 1): no staging; vmcnt(4) covers A1(47)
  PH(0, 0, 1, 1, , );
  PH(0, 1, 0, 1, , asm volatile("s_waitcnt vmcnt(4)" ::: "memory"));
  PH(1, 1, 1, 0, , );
  PH(1, 0, 0, 1, , );

#undef PH
#undef STAGE

  // ---------- fused quantized-LSTM epilogue ----------
  const int hb = bn * 4 + wc;
  const int h = hb * 16 + lr;
  float bias[4];
#pragma unroll
  for (int g = 0; g < 4; ++g)
    bias[g] = biasC[bn * 256 + ((g >> 1) * 8 + wc * 2 + (g & 1)) * 16 + lr];
#pragma unroll
  for (int mh = 0; mh < 2; ++mh) {
#pragma unroll
    for (int m2 = 0; m2 < 4; ++m2) {
      const int m = mh * 4 + m2;
#pragma unroll
      for (int r = 0; r < 4; ++r) {
        const int row = mbase + mh * 128 + wr * 64 + m2 * 16 + lg * 4 + r;
        const float gi = acc[m][0][r] + bias[0];
        const float gf = acc[m][1][r] + bias[1];
        const float gc = acc[m][2][r] + bias[2];
        const float go = acc[m][3][r] + bias[3];
        const float ig = fq_u(sigm(gi));
        const float fg = fq_u(sigm(gf));
        const float cg = fq_s(tanhf(gc));
        const float og = fq_u(sigm(go));
        const float cxv = cx[(size_t)row * HD + h];
        const float t1 = fq_s(fg * cxv);
        const float t2 = fq_s(ig * cg);
        const float cyv = fq_s((t1 + t2) * 0.5f);
        const float hyv = fq_s(og * fq_s(tanhf(cyv * 2.0f)));
        out[(size_t)row * HD + h] = hyv;
        out[HY_OFF + (size_t)row * HD + h] = cyv;
      }
    }
  }
}

// ---------- launch ----------
extern "C" void kernel_launch(void* const* d_in, const int* in_sizes, int n_in,
                              void* d_out, int out_size, void* d_ws, size_t ws_size,
                              hipStream_t stream) {
  const float* input = (const float*)d_in[0];
  const float* hx    = (const float*)d_in[1];
  const float* cx    = (const float*)d_in[2];
  const float* w_ih  = (const float*)d_in[3];
  const float* w_hh  = (const float*)d_in[4];
  const float* b_ih  = (const float*)d_in[5];
  const float* b_hh  = (const float*)d_in[6];
  const float* n_ih  = (const float*)d_in[7];
  const float* n_hh  = (const float*)d_in[8];
  const float* nb_ih = (const float*)d_in[9];
  const float* nb_hh = (const float*)d_in[10];
  float* out = (float*)d_out;

  char* ws = (char*)d_ws;
  float* maxes = (float*)ws;                                   // 16 B (+pad to 256)
  u16* Xhi = (u16*)(ws + 256);                                 // 16 MB
  u16* Xlo = (u16*)(ws + 256 + 16777216);                      // 16 MB
  u16* Whi = (u16*)(ws + 256 + 2 * 16777216);                  // 4 MB
  u16* Wlo = (u16*)(ws + 256 + 2 * 16777216 + 4194304);        // 4 MB
  float* biasC = (float*)(ws + 256 + 2 * 16777216 + 2 * 4194304); // 8 KB

  hipMemsetAsync(maxes, 0xFF, 16, stream);  // -NaN sentinel; atomic lattice fixes it
  hipLaunchKernelGGL(k_reduce_max, dim3(2052), dim3(256), 0, stream,
                     w_ih, w_hh, b_ih, b_hh, maxes);
  hipLaunchKernelGGL(k_split_x, dim3(2048), dim3(256), 0, stream, input, hx, Xhi, Xlo);
  hipLaunchKernelGGL(k_build_w, dim3(2048), dim3(256), 0, stream,
                     w_ih, w_hh, n_ih, n_hh, maxes, Whi, Wlo);
  hipLaunchKernelGGL(k_build_bias, dim3(8), dim3(256), 0, stream,
                     b_ih, b_hh, nb_ih, nb_hh, maxes, biasC);
  hipLaunchKernelGGL(k_gemm_lstm, dim3(256), dim3(512), 0, stream,
                     Xhi, Xlo, Whi, Wlo, biasC, cx, out);
}

// Round 3
// 151.982 us; speedup vs baseline: 1.3845x; 1.1003x over previous
//
#include <hip/hip_runtime.h>
#include <cstdint>

typedef unsigned short u16;
typedef __bf16 bf16x8 __attribute__((ext_vector_type(8)));
typedef float f32x4 __attribute__((ext_vector_type(4)));

#define NB 8192          // batch rows
#define HD 512           // hidden
#define KD 1024          // IN + H
#define ND 2048          // 4H (physical, column-reordered)
#define HY_OFF (NB * HD) // offset of cy in d_out
#define NT 32            // K-tiles of BK=32

// ---------- helpers ----------
__device__ __forceinline__ u16 f2bf(float f) {
  unsigned u = __float_as_uint(f);
  u += 0x7FFFu + ((u >> 16) & 1u);          // round-to-nearest-even bf16
  return (u16)(u >> 16);
}
__device__ __forceinline__ float bf2f(u16 h) {
  return __uint_as_float(((unsigned)h) << 16);
}
__device__ __forceinline__ void atomicMaxF(float* a, float v) {
  if (v >= 0.f) atomicMax((int*)a, __float_as_int(v));
  else          atomicMin((unsigned int*)a, __float_as_uint(v));
}
__device__ __forceinline__ float fq_u(float x) {           // unsigned 8-bit fake-quant
  float xc = fminf(fmaxf(x, 0.0f), 1.0f);
  return rintf(xc * 256.0f) * (1.0f / 256.0f);
}
__device__ __forceinline__ float fq_s(float x) {           // signed 8-bit fake-quant
  const float lim = 1.0f - 1.0f / 128.0f;
  float xc = fminf(fmaxf(x, -lim), lim);
  return rintf(xc * 128.0f) * (1.0f / 128.0f);
}
__device__ __forceinline__ float sigm(float x) { return 1.0f / (1.0f + expf(-x)); }

__device__ __forceinline__ void gload_lds16(const u16* g, u16* l) {
  __builtin_amdgcn_global_load_lds(
      (const __attribute__((address_space(1))) void*)g,
      (__attribute__((address_space(3))) void*)l, 16, 0, 0);
}

// ---------- max reductions (4 tensors -> maxes[0..3]) ----------
__global__ __launch_bounds__(256) void k_prep_max(
    const float* __restrict__ w_ih, const float* __restrict__ w_hh,
    const float* __restrict__ b_ih, const float* __restrict__ b_hh,
    float* __restrict__ maxes) {
  int bid = blockIdx.x;
  const float* src; int slot, base;
  if (bid < 1024)      { src = w_ih; slot = 0; base = bid * 1024; }
  else if (bid < 2048) { src = w_hh; slot = 1; base = (bid - 1024) * 1024; }
  else if (bid < 2050) { src = b_ih; slot = 2; base = (bid - 2048) * 1024; }
  else                 { src = b_hh; slot = 3; base = (bid - 2050) * 1024; }
  float m = -INFINITY;
  for (int i = threadIdx.x; i < 1024; i += 256) m = fmaxf(m, src[base + i]);
  for (int k = 1; k < 64; k <<= 1) m = fmaxf(m, __shfl_xor(m, k, 64));
  __shared__ float sm[4];
  if ((threadIdx.x & 63) == 0) sm[threadIdx.x >> 6] = m;
  __syncthreads();
  if (threadIdx.x == 0) {
    m = fmaxf(fmaxf(sm[0], sm[1]), fmaxf(sm[2], sm[3]));
    atomicMaxF(&maxes[slot], m);
  }
}

// ---------- fused prep: split X hi/lo + build W hi/lo + combined bias ----------
// blocks [0,2048): split X ; [2048,4096): W column j=bid-2048 ; [4096,4104): bias
// W physical j bits: [10:8]=bn, [7]=nh, [6:5]=wc, [4]=n2, [3:0]=lane
// gate g = 2*nh + n2 ; h-block hb = bn*4 + wc ; logical col = g*512 + hb*16 + lane
__global__ __launch_bounds__(256) void k_prep_build(
    const float* __restrict__ input, const float* __restrict__ hx,
    const float* __restrict__ w_ih, const float* __restrict__ w_hh,
    const float* __restrict__ n_ih, const float* __restrict__ n_hh,
    const float* __restrict__ b_ih, const float* __restrict__ b_hh,
    const float* __restrict__ nb_ih, const float* __restrict__ nb_hh,
    const float* __restrict__ maxes,
    u16* __restrict__ Xhi, u16* __restrict__ Xlo,
    u16* __restrict__ Whi, u16* __restrict__ Wlo,
    float* __restrict__ biasC) {
  const int bid = blockIdx.x;
  if (bid < 2048) {
    const int total4 = NB * KD / 4;
    for (int e4 = bid * 256 + threadIdx.x; e4 < total4; e4 += 2048 * 256) {
      int row = e4 >> 8;
      int c4  = e4 & 255;
      float4 v = (c4 < 128)
          ? reinterpret_cast<const float4*>(input)[row * 128 + c4]
          : reinterpret_cast<const float4*>(hx)[row * 128 + (c4 - 128)];
      float xs[4] = {v.x, v.y, v.z, v.w};
      ushort4 hi, lo;
      u16 h0 = f2bf(xs[0]); u16 l0 = f2bf(xs[0] - bf2f(h0));
      u16 h1 = f2bf(xs[1]); u16 l1 = f2bf(xs[1] - bf2f(h1));
      u16 h2 = f2bf(xs[2]); u16 l2 = f2bf(xs[2] - bf2f(h2));
      u16 h3 = f2bf(xs[3]); u16 l3 = f2bf(xs[3] - bf2f(h3));
      hi.x = h0; hi.y = h1; hi.z = h2; hi.w = h3;
      lo.x = l0; lo.y = l1; lo.z = l2; lo.w = l3;
      reinterpret_cast<ushort4*>(Xhi)[e4] = hi;
      reinterpret_cast<ushort4*>(Xlo)[e4] = lo;
    }
  } else if (bid < 4096) {
    int j  = bid - 2048;
    int g  = ((j >> 7) & 1) * 2 + ((j >> 4) & 1);
    int hb = ((j >> 8) << 2) | ((j >> 5) & 3);
    int col = g * 512 + (hb << 4) + (j & 15);
    float s_ih = maxes[0] * 0.1f, s_hh = maxes[1] * 0.1f;
    int k = threadIdx.x * 4;
    float4 wv; float nv[4]; float s;
    if (k < 512) {
      wv = reinterpret_cast<const float4*>(w_ih)[(col * 512 + k) >> 2];
#pragma unroll
      for (int q = 0; q < 4; ++q) nv[q] = n_ih[(k + q) * ND + col];
      s = s_ih;
    } else {
      int kk = k - 512;
      wv = reinterpret_cast<const float4*>(w_hh)[(col * 512 + kk) >> 2];
#pragma unroll
      for (int q = 0; q < 4; ++q) nv[q] = n_hh[(kk + q) * ND + col];
      s = s_hh;
    }
    float xs[4] = {wv.x + nv[0] * s, wv.y + nv[1] * s, wv.z + nv[2] * s, wv.w + nv[3] * s};
    ushort4 hi, lo;
    u16 h0 = f2bf(xs[0]); u16 l0 = f2bf(xs[0] - bf2f(h0));
    u16 h1 = f2bf(xs[1]); u16 l1 = f2bf(xs[1] - bf2f(h1));
    u16 h2 = f2bf(xs[2]); u16 l2 = f2bf(xs[2] - bf2f(h2));
    u16 h3 = f2bf(xs[3]); u16 l3 = f2bf(xs[3] - bf2f(h3));
    hi.x = h0; hi.y = h1; hi.z = h2; hi.w = h3;
    lo.x = l0; lo.y = l1; lo.z = l2; lo.w = l3;
    reinterpret_cast<ushort4*>(Whi)[(j * KD + k) >> 2] = hi;
    reinterpret_cast<ushort4*>(Wlo)[(j * KD + k) >> 2] = lo;
  } else {
    int j = (bid - 4096) * 256 + threadIdx.x;
    if (j < ND) {
      int g  = ((j >> 7) & 1) * 2 + ((j >> 4) & 1);
      int hb = ((j >> 8) << 2) | ((j >> 5) & 3);
      int col = g * 512 + (hb << 4) + (j & 15);
      biasC[j] = b_ih[col] + nb_ih[col] * (maxes[2] * 0.1f)
               + b_hh[col] + nb_hh[col] * (maxes[3] * 0.1f);
    }
  }
}

// ---------- GEMM 256x256-tile, BK=32 unified (Ahi/Alo/Bhi/Blo per tile) ----------
// grid 256; 512 threads (8 waves, 2x4); LDS 128 KiB = 2 slots x 4 bufs x 16 KB.
// LDS layout per buf: [128 lds-rows][64 u16] (= global row pairs); swizzle:
// chunk c' = c ^ (ldsrow & 7), applied on gload SOURCE and ds_read address.
// Per K=32 tile: 4 phases x 24 MFMA (3 terms: hihi + lohi + hilo).
__global__ __launch_bounds__(512, 2) void k_gemm_lstm(
    const u16* __restrict__ Xhi, const u16* __restrict__ Xlo,
    const u16* __restrict__ Whi, const u16* __restrict__ Wlo,
    const float* __restrict__ biasC, const float* __restrict__ cx,
    float* __restrict__ out) {
  __shared__ u16 L[2][4][8192];   // [slot][Ahi,Alo,Bhi,Blo][128x64]
  const int tid  = threadIdx.x;
  const int lane = tid & 63, wid = tid >> 6;
  const int wr = wid >> 2, wc = wid & 3;       // 2 x 4 waves
  const int lr = lane & 15, lg = lane >> 4;
  // XCD-region map: xcd = blk%8 owns an 8bm x 4bn region (bijective)
  const int xcd = blockIdx.x & 7, tt = blockIdx.x >> 3;
  const int bm = ((xcd >> 1) << 3) | (tt & 7);   // 0..31
  const int bn = ((xcd & 1) << 2) | (tt >> 3);   // 0..7
  const int mbase = bm * 256, nbase = bn * 256;

  // staging consts: lane l -> ldsrow (l>>3), lds chunk l&7, src chunk (l&7)^(l>>3)
  const int l8 = lane >> 3, l7 = lane & 7;
  const int csrc  = l7 ^ l8;
  const int srow  = wid * 16 + 2 * l8 + (csrc >> 2);  // global row offset in panel
  const int skoff = (csrc & 3) * 8;                   // k offset (u16)
  const int sdst  = wid * 512;                        // + HALF*4096 (u16)

  // frag-read per-thread swizzled offset (u16): row pair + chunk XOR
  const int fro = (lr >> 1) * 64 + ((((lr & 1) << 2) | lg) ^ ((lr >> 1) & 7)) * 8;

  f32x4 acc[8][4] = {};     // [mh*4+m2][gate = 2*nh+n2]
  bf16x8 afr[4][2];         // [m2][hi/lo]
  bf16x8 bfr[2][2][2];      // [nh][n2][hi/lo]

#define STAGE(V, BUF, HALF)                                                   \
  {                                                                           \
    const u16* arr_ = (BUF) == 0 ? Xhi : (BUF) == 1 ? Xlo                     \
                      : (BUF) == 2 ? Whi : Wlo;                               \
    const int gb_ = ((BUF) < 2 ? mbase : nbase) + (HALF) * 128 + srow;        \
    gload_lds16(arr_ + (size_t)gb_ * KD + (V) * 32 + skoff,                   \
                &L[(V) & 1][(BUF)][(HALF) * 4096 + sdst]);                    \
  }

#define PH(MH, NH, LOADA, LOADB, STAGE_CODE, WAIT_CODE)                       \
  {                                                                           \
    if (LOADA) {                                                              \
      _Pragma("unroll") for (int m2 = 0; m2 < 4; ++m2) {                      \
        const int ab = ((MH) * 128 + wr * 64 + m2 * 16) * 32 + fro;           \
        afr[m2][0] = *reinterpret_cast<const bf16x8*>(&L[s][0][ab]);          \
        afr[m2][1] = *reinterpret_cast<const bf16x8*>(&L[s][1][ab]);          \
      }                                                                       \
    }                                                                         \
    if (LOADB) {                                                              \
      _Pragma("unroll") for (int n2 = 0; n2 < 2; ++n2) {                      \
        const int bb = ((NH) * 128 + wc * 32 + n2 * 16) * 32 + fro;           \
        bfr[(NH)][n2][0] = *reinterpret_cast<const bf16x8*>(&L[s][2][bb]);    \
        bfr[(NH)][n2][1] = *reinterpret_cast<const bf16x8*>(&L[s][3][bb]);    \
      }                                                                       \
    }                                                                         \
    STAGE_CODE;                                                               \
    WAIT_CODE;                                                                \
    __builtin_amdgcn_s_barrier();                                             \
    __builtin_amdgcn_s_setprio(1);                                            \
    _Pragma("unroll") for (int m2 = 0; m2 < 4; ++m2)                          \
      _Pragma("unroll") for (int n2 = 0; n2 < 2; ++n2) {                      \
        f32x4* ac = &acc[(MH) * 4 + m2][(NH) * 2 + n2];                       \
        *ac = __builtin_amdgcn_mfma_f32_16x16x32_bf16(afr[m2][0],             \
                  bfr[(NH)][n2][0], *ac, 0, 0, 0);                            \
        *ac = __builtin_amdgcn_mfma_f32_16x16x32_bf16(afr[m2][1],             \
                  bfr[(NH)][n2][0], *ac, 0, 0, 0);                            \
        *ac = __builtin_amdgcn_mfma_f32_16x16x32_bf16(afr[m2][0],             \
                  bfr[(NH)][n2][1], *ac, 0, 0, 0);                            \
      }                                                                       \
    __builtin_amdgcn_s_setprio(0);                                            \
    __builtin_amdgcn_s_barrier();                                             \
  }

  // prologue: stage tile 0 in consumption order P1..P8
  STAGE(0, 0, 0); STAGE(0, 1, 0);   // Ahi.h0, Alo.h0
  STAGE(0, 2, 0); STAGE(0, 3, 0);   // Bhi.h0, Blo.h0
  STAGE(0, 2, 1); STAGE(0, 3, 1);   // Bhi.h1, Blo.h1
  STAGE(0, 0, 1); STAGE(0, 1, 1);   // Ahi.h1, Alo.h1
  asm volatile("s_waitcnt vmcnt(4)" ::: "memory");   // P1..P4 landed
  __builtin_amdgcn_s_barrier();

  int s = 0;
  for (int u = 0; u < NT - 1; ++u, s ^= 1) {
    // ph0 (mh0,nh0): reads P1..P4 data; stage N1,N2; wait -> P5,P6 for ph1
    PH(0, 0, 1, 1, { STAGE(u + 1, 0, 0); STAGE(u + 1, 1, 0); },
       asm volatile("s_waitcnt vmcnt(4)" ::: "memory"));
    // ph1 (mh0,nh1): reads P5,P6; stage N3,N4; wait -> P7,P8 for ph2
    PH(0, 1, 0, 1, { STAGE(u + 1, 2, 0); STAGE(u + 1, 3, 0); },
       asm volatile("s_waitcnt vmcnt(4)" ::: "memory"));
    // ph2 (mh1,nh1): reads P7,P8; stage N5,N6; no wait
    PH(1, 1, 1, 0, { STAGE(u + 1, 2, 1); STAGE(u + 1, 3, 1); }, );
    // ph3 (mh1,nh0): no reads; stage N7,N8; wait -> N1..N4 for next ph0
    PH(1, 0, 0, 0, { STAGE(u + 1, 0, 1); STAGE(u + 1, 1, 1); },
       asm volatile("s_waitcnt vmcnt(4)" ::: "memory"));
  }
  // peeled tile NT-1 (s == 1): no staging; drain
  PH(0, 0, 1, 1, , asm volatile("s_waitcnt vmcnt(2)" ::: "memory"));
  PH(0, 1, 0, 1, , asm volatile("s_waitcnt vmcnt(0)" ::: "memory"));
  PH(1, 1, 1, 0, , );
  PH(1, 0, 0, 0, , );

#undef PH
#undef STAGE

  // ---------- fused quantized-LSTM epilogue ----------
  const int hb = bn * 4 + wc;
  const int h = hb * 16 + lr;
  float bias[4];
#pragma unroll
  for (int g = 0; g < 4; ++g)
    bias[g] = biasC[bn * 256 + ((g >> 1) * 8 + wc * 2 + (g & 1)) * 16 + lr];
#pragma unroll
  for (int mh = 0; mh < 2; ++mh) {
#pragma unroll
    for (int m2 = 0; m2 < 4; ++m2) {
      const int m = mh * 4 + m2;
#pragma unroll
      for (int r = 0; r < 4; ++r) {
        const int row = mbase + mh * 128 + wr * 64 + m2 * 16 + lg * 4 + r;
        const float gi = acc[m][0][r] + bias[0];
        const float gf = acc[m][1][r] + bias[1];
        const float gc = acc[m][2][r] + bias[2];
        const float go = acc[m][3][r] + bias[3];
        const float ig = fq_u(sigm(gi));
        const float fg = fq_u(sigm(gf));
        const float cg = fq_s(tanhf(gc));
        const float og = fq_u(sigm(go));
        const float cxv = cx[(size_t)row * HD + h];
        const float t1 = fq_s(fg * cxv);
        const float t2 = fq_s(ig * cg);
        const float cyv = fq_s((t1 + t2) * 0.5f);
        const float hyv = fq_s(og * fq_s(tanhf(cyv * 2.0f)));
        out[(size_t)row * HD + h] = hyv;
        out[HY_OFF + (size_t)row * HD + h] = cyv;
      }
    }
  }
}

// ---------- launch ----------
extern "C" void kernel_launch(void* const* d_in, const int* in_sizes, int n_in,
                              void* d_out, int out_size, void* d_ws, size_t ws_size,
                              hipStream_t stream) {
  const float* input = (const float*)d_in[0];
  const float* hx    = (const float*)d_in[1];
  const float* cx    = (const float*)d_in[2];
  const float* w_ih  = (const float*)d_in[3];
  const float* w_hh  = (const float*)d_in[4];
  const float* b_ih  = (const float*)d_in[5];
  const float* b_hh  = (const float*)d_in[6];
  const float* n_ih  = (const float*)d_in[7];
  const float* n_hh  = (const float*)d_in[8];
  const float* nb_ih = (const float*)d_in[9];
  const float* nb_hh = (const float*)d_in[10];
  float* out = (float*)d_out;

  char* ws = (char*)d_ws;
  float* maxes = (float*)ws;                                   // 16 B (+pad to 256)
  u16* Xhi = (u16*)(ws + 256);                                 // 16 MB
  u16* Xlo = (u16*)(ws + 256 + 16777216);                      // 16 MB
  u16* Whi = (u16*)(ws + 256 + 2 * 16777216);                  // 4 MB
  u16* Wlo = (u16*)(ws + 256 + 2 * 16777216 + 4194304);        // 4 MB
  float* biasC = (float*)(ws + 256 + 2 * 16777216 + 2 * 4194304); // 8 KB

  hipMemsetAsync(maxes, 0xFF, 16, stream);  // -NaN sentinel; atomic lattice fixes it
  hipLaunchKernelGGL(k_prep_max, dim3(2052), dim3(256), 0, stream,
                     w_ih, w_hh, b_ih, b_hh, maxes);
  hipLaunchKernelGGL(k_prep_build, dim3(4104), dim3(256), 0, stream,
                     input, hx, w_ih, w_hh, n_ih, n_hh, b_ih, b_hh,
                     nb_ih, nb_hh, maxes, Xhi, Xlo, Whi, Wlo, biasC);
  hipLaunchKernelGGL(k_gemm_lstm, dim3(256), dim3(512), 0, stream,
                     Xhi, Xlo, Whi, Wlo, biasC, cx, out);
}

// Round 4
// 150.753 us; speedup vs baseline: 1.3958x; 1.0082x over previous
//
#include <hip/hip_runtime.h>
#include <cstdint>

typedef unsigned short u16;
typedef __bf16 bf16x8 __attribute__((ext_vector_type(8)));
typedef float f32x4 __attribute__((ext_vector_type(4)));

#define NB 8192          // batch rows
#define HD 512           // hidden
#define KD 1024          // IN + H
#define ND 2048          // 4H (physical, column-reordered)
#define HY_OFF (NB * HD) // offset of cy in d_out
#define NT 32            // K-tiles of BK=32

// ---------- helpers ----------
__device__ __forceinline__ u16 f2bf(float f) {
  unsigned u = __float_as_uint(f);
  u += 0x7FFFu + ((u >> 16) & 1u);          // round-to-nearest-even bf16
  return (u16)(u >> 16);
}
__device__ __forceinline__ float bf2f(u16 h) {
  return __uint_as_float(((unsigned)h) << 16);
}
__device__ __forceinline__ void atomicMaxF(float* a, float v) {
  if (v >= 0.f) atomicMax((int*)a, __float_as_int(v));
  else          atomicMin((unsigned int*)a, __float_as_uint(v));
}
__device__ __forceinline__ float fq_u(float x) {           // unsigned 8-bit fake-quant
  float xc = fminf(fmaxf(x, 0.0f), 1.0f);
  return rintf(xc * 256.0f) * (1.0f / 256.0f);
}
__device__ __forceinline__ float fq_s(float x) {           // signed 8-bit fake-quant
  const float lim = 1.0f - 1.0f / 128.0f;
  float xc = fminf(fmaxf(x, -lim), lim);
  return rintf(xc * 128.0f) * (1.0f / 128.0f);
}
__device__ __forceinline__ float sigm(float x) { return 1.0f / (1.0f + expf(-x)); }

__device__ __forceinline__ void gload_lds16(const u16* g, u16* l) {
  __builtin_amdgcn_global_load_lds(
      (const __attribute__((address_space(1))) void*)g,
      (__attribute__((address_space(3))) void*)l, 16, 0, 0);
}

// ---------- max reductions (4 tensors -> maxes[0..3]) ----------
__global__ __launch_bounds__(256) void k_prep_max(
    const float* __restrict__ w_ih, const float* __restrict__ w_hh,
    const float* __restrict__ b_ih, const float* __restrict__ b_hh,
    float* __restrict__ maxes) {
  int bid = blockIdx.x;
  const float* src; int slot, base;
  if (bid < 1024)      { src = w_ih; slot = 0; base = bid * 1024; }
  else if (bid < 2048) { src = w_hh; slot = 1; base = (bid - 1024) * 1024; }
  else if (bid < 2050) { src = b_ih; slot = 2; base = (bid - 2048) * 1024; }
  else                 { src = b_hh; slot = 3; base = (bid - 2050) * 1024; }
  float m = -INFINITY;
  for (int i = threadIdx.x; i < 1024; i += 256) m = fmaxf(m, src[base + i]);
  for (int k = 1; k < 64; k <<= 1) m = fmaxf(m, __shfl_xor(m, k, 64));
  __shared__ float sm[4];
  if ((threadIdx.x & 63) == 0) sm[threadIdx.x >> 6] = m;
  __syncthreads();
  if (threadIdx.x == 0) {
    m = fmaxf(fmaxf(sm[0], sm[1]), fmaxf(sm[2], sm[3]));
    atomicMaxF(&maxes[slot], m);
  }
}

// ---------- fused prep: split X hi/lo + build W hi/lo (coalesced) + bias ----------
// blocks [0,2048): split X ; [2048,2176): W 16-col groups ; [2176,2184): bias
// W physical j bits: [10:8]=bn, [7]=nh, [6:5]=wc, [4]=n2, [3:0]=lane
// gate g = 2*nh + n2 ; h-block hb = bn*4 + wc ; logical col = g*512 + hb*16 + lane
__global__ __launch_bounds__(256) void k_prep_build(
    const float* __restrict__ input, const float* __restrict__ hx,
    const float* __restrict__ w_ih, const float* __restrict__ w_hh,
    const float* __restrict__ n_ih, const float* __restrict__ n_hh,
    const float* __restrict__ b_ih, const float* __restrict__ b_hh,
    const float* __restrict__ nb_ih, const float* __restrict__ nb_hh,
    const float* __restrict__ maxes,
    u16* __restrict__ Xhi, u16* __restrict__ Xlo,
    u16* __restrict__ Whi, u16* __restrict__ Wlo,
    float* __restrict__ biasC) {
  const int bid = blockIdx.x;
  if (bid < 2048) {
    const int total4 = NB * KD / 4;
    for (int e4 = bid * 256 + threadIdx.x; e4 < total4; e4 += 2048 * 256) {
      int row = e4 >> 8;
      int c4  = e4 & 255;
      float4 v = (c4 < 128)
          ? reinterpret_cast<const float4*>(input)[row * 128 + c4]
          : reinterpret_cast<const float4*>(hx)[row * 128 + (c4 - 128)];
      float xs[4] = {v.x, v.y, v.z, v.w};
      ushort4 hi, lo;
      u16 h0 = f2bf(xs[0]); u16 l0 = f2bf(xs[0] - bf2f(h0));
      u16 h1 = f2bf(xs[1]); u16 l1 = f2bf(xs[1] - bf2f(h1));
      u16 h2 = f2bf(xs[2]); u16 l2 = f2bf(xs[2] - bf2f(h2));
      u16 h3 = f2bf(xs[3]); u16 l3 = f2bf(xs[3] - bf2f(h3));
      hi.x = h0; hi.y = h1; hi.z = h2; hi.w = h3;
      lo.x = l0; lo.y = l1; lo.z = l2; lo.w = l3;
      reinterpret_cast<ushort4*>(Xhi)[e4] = hi;
      reinterpret_cast<ushort4*>(Xlo)[e4] = lo;
    }
  } else if (bid < 2176) {
    // 16 physical cols j0..j0+15 (one lane-group) = 16 consecutive logical cols
    __shared__ float nT[1024][17];   // padded: 2-way-free on read
    const int w  = bid - 2048;
    const int j0 = w * 16;
    const int g  = ((j0 >> 7) & 1) * 2 + ((j0 >> 4) & 1);
    const int hb = ((j0 >> 8) << 2) | ((j0 >> 5) & 3);
    const int col0 = g * 512 + (hb << 4);
    {  // stage noise[k][col0..col0+16) -> nT, coalesced (64B per 16-lane group)
      const int cl = threadIdx.x & 15;
      const int kr = threadIdx.x >> 4;
#pragma unroll 4
      for (int i = 0; i < 64; ++i) {
        const int k = kr + 16 * i;
        nT[k][cl] = (k < 512) ? n_ih[k * ND + col0 + cl]
                              : n_hh[(k - 512) * ND + col0 + cl];
      }
    }
    __syncthreads();
    const float s_ih = maxes[0] * 0.1f, s_hh = maxes[1] * 0.1f;
    const int c  = threadIdx.x >> 4;       // col 0..15
    const int kl = threadIdx.x & 15;
    const int colL = col0 + c;
    const int j = j0 + c;
#pragma unroll 4
    for (int kk = 0; kk < 16; ++kk) {
      const int k = kk * 64 + kl * 4;
      float4 wv; float s;
      if (k < 512) {
        wv = reinterpret_cast<const float4*>(w_ih)[(colL * 512 + k) >> 2];
        s = s_ih;
      } else {
        wv = reinterpret_cast<const float4*>(w_hh)[(colL * 512 + k - 512) >> 2];
        s = s_hh;
      }
      float xs[4] = {wv.x + nT[k + 0][c] * s, wv.y + nT[k + 1][c] * s,
                     wv.z + nT[k + 2][c] * s, wv.w + nT[k + 3][c] * s};
      ushort4 hi, lo;
      u16 h0 = f2bf(xs[0]); u16 l0 = f2bf(xs[0] - bf2f(h0));
      u16 h1 = f2bf(xs[1]); u16 l1 = f2bf(xs[1] - bf2f(h1));
      u16 h2 = f2bf(xs[2]); u16 l2 = f2bf(xs[2] - bf2f(h2));
      u16 h3 = f2bf(xs[3]); u16 l3 = f2bf(xs[3] - bf2f(h3));
      hi.x = h0; hi.y = h1; hi.z = h2; hi.w = h3;
      lo.x = l0; lo.y = l1; lo.z = l2; lo.w = l3;
      reinterpret_cast<ushort4*>(Whi)[(j * KD + k) >> 2] = hi;
      reinterpret_cast<ushort4*>(Wlo)[(j * KD + k) >> 2] = lo;
    }
  } else {
    int j = (bid - 2176) * 256 + threadIdx.x;
    if (j < ND) {
      int g  = ((j >> 7) & 1) * 2 + ((j >> 4) & 1);
      int hb = ((j >> 8) << 2) | ((j >> 5) & 3);
      int col = g * 512 + (hb << 4) + (j & 15);
      biasC[j] = b_ih[col] + nb_ih[col] * (maxes[2] * 0.1f)
               + b_hh[col] + nb_hh[col] * (maxes[3] * 0.1f);
    }
  }
}

// ---------- GEMM 256x256-tile, BK=32 unified, 2 phases/tile ----------
// grid 256; 512 threads (8 waves, 2x4); LDS 128 KiB = 2 slots x 4 bufs x 16 KB.
// ph0 (mh0): read A-h0 frags (8 b128) + ALL B frags (8 b128); 48 MFMA.
// ph1 (mh1): read A-h1 frags (8 b128); B stays in regs; 48 MFMA.
// Stage issue: ph0 -> A-h0,B of tile u+1 (6 events); ph1 -> A-h1 (2 events).
// Waits: ph0 vmcnt(6) [covers ph1's A-h1 reads], ph1 vmcnt(2) [covers next ph0].
__global__ __launch_bounds__(512, 2) void k_gemm_lstm(
    const u16* __restrict__ Xhi, const u16* __restrict__ Xlo,
    const u16* __restrict__ Whi, const u16* __restrict__ Wlo,
    const float* __restrict__ biasC, const float* __restrict__ cx,
    float* __restrict__ out) {
  __shared__ u16 L[2][4][8192];   // [slot][Ahi,Alo,Bhi,Blo][128x64]
  const int tid  = threadIdx.x;
  const int lane = tid & 63, wid = tid >> 6;
  const int wr = wid >> 2, wc = wid & 3;       // 2 x 4 waves
  const int lr = lane & 15, lg = lane >> 4;
  // XCD-region map: xcd = blk%8 owns an 8bm x 4bn region (bijective)
  const int xcd = blockIdx.x & 7, tt = blockIdx.x >> 3;
  const int bm = ((xcd >> 1) << 3) | (tt & 7);   // 0..31
  const int bn = ((xcd & 1) << 2) | (tt >> 3);   // 0..7
  const int mbase = bm * 256, nbase = bn * 256;

  // staging consts: lane l -> ldsrow (l>>3), lds chunk l&7, src chunk (l&7)^(l>>3)
  const int l8 = lane >> 3, l7 = lane & 7;
  const int csrc  = l7 ^ l8;
  const int srow  = wid * 16 + 2 * l8 + (csrc >> 2);  // global row offset in panel
  const int skoff = (csrc & 3) * 8;                   // k offset (u16)
  const int sdst  = wid * 512;                        // + HALF*4096 (u16)

  // frag-read per-thread swizzled offset (u16): row pair + chunk XOR
  const int fro = (lr >> 1) * 64 + ((((lr & 1) << 2) | lg) ^ ((lr >> 1) & 7)) * 8;

  f32x4 acc[8][4] = {};     // [mh*4+m2][gate = 2*nh+n2]
  bf16x8 afr[4][2];         // [m2][hi/lo]
  bf16x8 bfr[2][2][2];      // [nh][n2][hi/lo], live across both phases

#define STAGE(V, BUF, HALF)                                                   \
  {                                                                           \
    const u16* arr_ = (BUF) == 0 ? Xhi : (BUF) == 1 ? Xlo                     \
                      : (BUF) == 2 ? Whi : Wlo;                               \
    const int gb_ = ((BUF) < 2 ? mbase : nbase) + (HALF) * 128 + srow;        \
    gload_lds16(arr_ + (size_t)gb_ * KD + (V) * 32 + skoff,                   \
                &L[(V) & 1][(BUF)][(HALF) * 4096 + sdst]);                    \
  }

#define PH2(MH, STAGE_CODE, WAIT_CODE)                                       \
  {                                                                          \
    _Pragma("unroll") for (int m2 = 0; m2 < 4; ++m2) {                       \
      const int ab = ((MH) * 128 + wr * 64 + m2 * 16) * 32 + fro;            \
      afr[m2][0] = *reinterpret_cast<const bf16x8*>(&L[s][0][ab]);           \
      afr[m2][1] = *reinterpret_cast<const bf16x8*>(&L[s][1][ab]);           \
    }                                                                        \
    if ((MH) == 0) {                                                         \
      _Pragma("unroll") for (int nh = 0; nh < 2; ++nh)                       \
        _Pragma("unroll") for (int n2 = 0; n2 < 2; ++n2) {                   \
          const int bb = (nh * 128 + wc * 32 + n2 * 16) * 32 + fro;          \
          bfr[nh][n2][0] = *reinterpret_cast<const bf16x8*>(&L[s][2][bb]);   \
          bfr[nh][n2][1] = *reinterpret_cast<const bf16x8*>(&L[s][3][bb]);   \
        }                                                                    \
    }                                                                        \
    STAGE_CODE;                                                              \
    WAIT_CODE;                                                               \
    __builtin_amdgcn_s_barrier();                                            \
    __builtin_amdgcn_s_setprio(1);                                           \
    _Pragma("unroll") for (int t = 0; t < 3; ++t)                            \
      _Pragma("unroll") for (int m2 = 0; m2 < 4; ++m2)                       \
        _Pragma("unroll") for (int nh = 0; nh < 2; ++nh)                     \
          _Pragma("unroll") for (int n2 = 0; n2 < 2; ++n2) {                 \
            f32x4* ac = &acc[(MH) * 4 + m2][nh * 2 + n2];                    \
            *ac = __builtin_amdgcn_mfma_f32_16x16x32_bf16(                   \
                afr[m2][t == 1], bfr[nh][n2][t == 2], *ac, 0, 0, 0);         \
          }                                                                  \
    __builtin_amdgcn_s_setprio(0);                                           \
    __builtin_amdgcn_s_barrier();                                            \
  }

  // prologue: stage tile 0 (8 events, consumption order)
  STAGE(0, 0, 0); STAGE(0, 1, 0);             // A-h0 hi,lo
  STAGE(0, 2, 0); STAGE(0, 2, 1);             // Bhi h0,h1
  STAGE(0, 3, 0); STAGE(0, 3, 1);             // Blo h0,h1
  STAGE(0, 0, 1); STAGE(0, 1, 1);             // A-h1 hi,lo
  asm volatile("s_waitcnt vmcnt(2)" ::: "memory");   // first 6 landed
  __builtin_amdgcn_s_barrier();

  int s = 0;
  for (int u = 0; u < NT - 1; ++u, s ^= 1) {
    PH2(0,
        { STAGE(u + 1, 0, 0); STAGE(u + 1, 1, 0);
          STAGE(u + 1, 2, 0); STAGE(u + 1, 2, 1);
          STAGE(u + 1, 3, 0); STAGE(u + 1, 3, 1); },
        asm volatile("s_waitcnt vmcnt(6)" ::: "memory"));
    PH2(1,
        { STAGE(u + 1, 0, 1); STAGE(u + 1, 1, 1); },
        asm volatile("s_waitcnt vmcnt(2)" ::: "memory"));
  }
  // peeled last tile (s == 1): no staging
  PH2(0, , asm volatile("s_waitcnt vmcnt(0)" ::: "memory"));
  PH2(1, , );

#undef PH2
#undef STAGE

  // ---------- fused quantized-LSTM epilogue ----------
  const int hb = bn * 4 + wc;
  const int h = hb * 16 + lr;
  float bias[4];
#pragma unroll
  for (int g = 0; g < 4; ++g)
    bias[g] = biasC[bn * 256 + ((g >> 1) * 8 + wc * 2 + (g & 1)) * 16 + lr];
#pragma unroll
  for (int mh = 0; mh < 2; ++mh) {
#pragma unroll
    for (int m2 = 0; m2 < 4; ++m2) {
      const int m = mh * 4 + m2;
#pragma unroll
      for (int r = 0; r < 4; ++r) {
        const int row = mbase + mh * 128 + wr * 64 + m2 * 16 + lg * 4 + r;
        const float gi = acc[m][0][r] + bias[0];
        const float gf = acc[m][1][r] + bias[1];
        const float gc = acc[m][2][r] + bias[2];
        const float go = acc[m][3][r] + bias[3];
        const float ig = fq_u(sigm(gi));
        const float fg = fq_u(sigm(gf));
        const float cg = fq_s(tanhf(gc));
        const float og = fq_u(sigm(go));
        const float cxv = cx[(size_t)row * HD + h];
        const float t1 = fq_s(fg * cxv);
        const float t2 = fq_s(ig * cg);
        const float cyv = fq_s((t1 + t2) * 0.5f);
        const float hyv = fq_s(og * fq_s(tanhf(cyv * 2.0f)));
        out[(size_t)row * HD + h] = hyv;
        out[HY_OFF + (size_t)row * HD + h] = cyv;
      }
    }
  }
}

// ---------- launch ----------
extern "C" void kernel_launch(void* const* d_in, const int* in_sizes, int n_in,
                              void* d_out, int out_size, void* d_ws, size_t ws_size,
                              hipStream_t stream) {
  const float* input = (const float*)d_in[0];
  const float* hx    = (const float*)d_in[1];
  const float* cx    = (const float*)d_in[2];
  const float* w_ih  = (const float*)d_in[3];
  const float* w_hh  = (const float*)d_in[4];
  const float* b_ih  = (const float*)d_in[5];
  const float* b_hh  = (const float*)d_in[6];
  const float* n_ih  = (const float*)d_in[7];
  const float* n_hh  = (const float*)d_in[8];
  const float* nb_ih = (const float*)d_in[9];
  const float* nb_hh = (const float*)d_in[10];
  float* out = (float*)d_out;

  char* ws = (char*)d_ws;
  float* maxes = (float*)ws;                                   // 16 B (+pad to 256)
  u16* Xhi = (u16*)(ws + 256);                                 // 16 MB
  u16* Xlo = (u16*)(ws + 256 + 16777216);                      // 16 MB
  u16* Whi = (u16*)(ws + 256 + 2 * 16777216);                  // 4 MB
  u16* Wlo = (u16*)(ws + 256 + 2 * 16777216 + 4194304);        // 4 MB
  float* biasC = (float*)(ws + 256 + 2 * 16777216 + 2 * 4194304); // 8 KB

  hipMemsetAsync(maxes, 0xFF, 16, stream);  // -NaN sentinel; atomic lattice fixes it
  hipLaunchKernelGGL(k_prep_max, dim3(2052), dim3(256), 0, stream,
                     w_ih, w_hh, b_ih, b_hh, maxes);
  hipLaunchKernelGGL(k_prep_build, dim3(2184), dim3(256), 0, stream,
                     input, hx, w_ih, w_hh, n_ih, n_hh, b_ih, b_hh,
                     nb_ih, nb_hh, maxes, Xhi, Xlo, Whi, Wlo, biasC);
  hipLaunchKernelGGL(k_gemm_lstm, dim3(256), dim3(512), 0, stream,
                     Xhi, Xlo, Whi, Wlo, biasC, cx, out);
}